// Round 2
// baseline (386.830 us; speedup 1.0000x reference)
//
#include <hip/hip_runtime.h>

// B=8, N=256, D=128
// out[b,i,d] = sum_e T[b,i,e]*W[e,d] + bias[d]
//   T[b,i,e]  = sum_j adj[b,i,j] * (hidden[b,j,e] + dep[b,j,i,e])
//
// Two-pass, j-major dep streaming. A/B vs round 1: the ONLY change is
// nontemporal loads -> plain loads on the dep stream. Round 0 (512-B
// strided NT reads) and round 1 (32-KB contiguous NT reads) both landed
// at ~2.3 TB/s effective dep BW -> the shared suspect is the NT flag
// itself (L2-bypass path throttling request throughput on gfx950).
// dep is read once, so losing the NT hint costs nothing in L2 terms.

constexpr int Bc = 8;
constexpr int Nc = 256;
constexpr int Dc = 128;
constexpr int JC  = 8;          // j per chunk
constexpr int NCH = Nc / JC;    // 32 chunks
constexpr int ISP = 4;          // i splits
constexpr int IW  = Nc / ISP;   // 64 i-rows per block

typedef float floatx4 __attribute__((ext_vector_type(4)));

// U layout: [jc][b][ih][il][e]  (jc-stride = 1 MB; block writes 32 KB coalesced)
__global__ __launch_bounds__(256) void depgcn_pass1(
    const float* __restrict__ hidden,  // [B,N,D]
    const float* __restrict__ adj,     // [B,N,N]
    const float* __restrict__ dep,     // [B,N,N,D]
    float* __restrict__ U)
{
    const int blk = blockIdx.x;            // b*128 + jc*4 + ih
    const int ih  = blk & (ISP - 1);
    const int jc  = (blk >> 2) & (NCH - 1);
    const int b   = blk >> 7;
    const int t   = threadIdx.x;           // 0..255

    const int i0 = ih * IW;
    const int j0 = jc * JC;

    __shared__ float sA[JC][IW];           // sA[jl][il] = adj[b, i0+il, j0+jl]
    {
        const int idx = t * 2;             // 512 elems, 2/thread (jl even -> jl+1 safe)
        const int il  = idx >> 3;
        const int jl  = idx & 7;
        const float* ap = adj + ((size_t)b * Nc + i0 + il) * Nc + j0 + jl;
        sA[jl][il]     = ap[0];
        sA[jl + 1][il] = ap[1];
    }
    __syncthreads();

    floatx4 acc[8];
    #pragma unroll
    for (int k = 0; k < 8; ++k) acc[k] = {0.f, 0.f, 0.f, 0.f};

    const int e4 = (t & 31) * 4;           // this thread's e-offset (const over k)
    const int r0 = t >> 5;                 // i_local base; i_local = r0 + 8k

    // dep panel for (b, j0+jl): 32 KB contiguous; thread covers f4 = t + k*256
    const float* depBase = dep + (((size_t)(b * Nc + j0)) * Nc + i0) * Dc + t * 4;
    const float* hidBase = hidden + ((size_t)(b * Nc + j0)) * Dc + e4;

    for (int jl = 0; jl < JC; ++jl) {
        const float* dp = depBase + (size_t)jl * Nc * Dc;
        floatx4 d[8];
        #pragma unroll
        for (int k = 0; k < 8; ++k)
            d[k] = *(const floatx4*)(dp + k * 1024);   // plain (cached) load — the A/B
        const floatx4 h = *(const floatx4*)(hidBase + (size_t)jl * Dc);
        #pragma unroll
        for (int k = 0; k < 8; ++k) {
            const float a = sA[jl][r0 + k * 8];   // 2 addrs per wave: LDS broadcast
            acc[k] += a * (d[k] + h);
        }
    }

    // coalesced 32 KB partial write
    float* up = U + (((size_t)jc * Bc + b) * ISP + ih) * (IW * Dc) + t * 4;
    #pragma unroll
    for (int k = 0; k < 8; ++k)
        *(floatx4*)(up + k * 1024) = acc[k];
}

__global__ __launch_bounds__(128) void depgcn_pass2(
    const float* __restrict__ U,
    const float* __restrict__ W,       // [D,D]
    const float* __restrict__ bias,    // [D]
    float* __restrict__ out)           // [B,N,D]
{
    const int bi = blockIdx.x;         // 0..B*N-1
    const int b  = bi >> 8;
    const int i  = bi & (Nc - 1);
    const int ih = i >> 6;
    const int il = i & (IW - 1);
    const int t  = threadIdx.x;        // 0..127 == e, then d

    __shared__ float sT[Dc];

    // reduce the 32 chunk-partials (just-written: L2/L3-resident)
    float s = 0.f;
    const float* up = U + ((size_t)b * ISP + ih) * (IW * Dc) + (size_t)il * Dc + t;
    #pragma unroll
    for (int jc = 0; jc < NCH; ++jc)
        s += up[(size_t)jc * (Bc * ISP * IW * Dc)];
    sT[t] = s;
    __syncthreads();

    // out[b,i,d] = sum_e sT[e]*W[e,d] + bias[d]
    float o = 0.f;
    const float* wp = W + t;
    #pragma unroll 16
    for (int e = 0; e < Dc; ++e)
        o = fmaf(sT[e], wp[(size_t)e * Dc], o);
    out[((size_t)b * Nc + i) * Dc + t] = o + bias[t];
}

extern "C" void kernel_launch(void* const* d_in, const int* in_sizes, int n_in,
                              void* d_out, int out_size, void* d_ws, size_t ws_size,
                              hipStream_t stream) {
    const float* hidden = (const float*)d_in[0];
    const float* adj    = (const float*)d_in[1];
    const float* dep    = (const float*)d_in[2];
    const float* W      = (const float*)d_in[3];
    const float* bias   = (const float*)d_in[4];
    float* out          = (float*)d_out;
    float* U            = (float*)d_ws;   // needs 33.5 MB (NCH * B*N*D * 4B)

    depgcn_pass1<<<dim3(Bc * NCH * ISP), dim3(256), 0, stream>>>(hidden, adj, dep, U);
    depgcn_pass2<<<dim3(Bc * Nc), dim3(128), 0, stream>>>(U, W, bias, out);
}

// Round 3
// 347.121 us; speedup vs baseline: 1.1144x; 1.1144x over previous
//
#include <hip/hip_runtime.h>

// B=8, N=256, D=128
// out[b,i,d] = sum_e T[b,i,e]*W[e,d] + bias[d]
//   T[b,i,e]  = sum_j adj[b,i,j] * (hidden[b,j,e] + dep[b,j,i,e])
//
// Fused single kernel, one block per (b, 8-row i-tile), ALL j inside:
//  - grid = 8*32 = 256 blocks (1/CU). Each j-step reads dep[b,j,i0:i0+8,:]
//    = 4 KB fully contiguous, nontemporal (dep read once grid-wide; NT also
//    avoids evicting the harness's dirty poison lines -> R2 showed plain
//    loads cost +28 us from writeback interference).
//  - T for the whole i-tile finishes in REGISTERS (no U workspace, no 2nd
//    launch, no cross-block reduce): saves the 67 MB U round-trip + launch.
//  - 8-deep NT unroll: 8 KB in flight/wave x 4 waves = 32 KB/CU >> the
//    ~8 KB needed to cover ~900cy HBM latency at 10.3 B/cy/CU.
//  - epilogue: T -> LDS, 128x128 W matvec (W hot in L2), bias, out.

constexpr int Bc = 8;
constexpr int Nc = 256;
constexpr int Dc = 128;
constexpr int IW = 8;            // i-rows per block
constexpr int NB = Nc / IW;      // 32 i-tiles

typedef float floatx4 __attribute__((ext_vector_type(4)));

__global__ __launch_bounds__(256) void depgcn_fused(
    const float* __restrict__ hidden,  // [B,N,D]
    const float* __restrict__ adj,     // [B,N,N]
    const float* __restrict__ dep,     // [B,N,N,D]
    const float* __restrict__ W,       // [D,D]
    const float* __restrict__ bias,    // [D]
    float* __restrict__ out)           // [B,N,D]
{
    const int blk = blockIdx.x;        // b*32 + ih
    const int ih  = blk & (NB - 1);
    const int b   = blk >> 5;
    const int t   = threadIdx.x;       // 0..255
    const int i0  = ih * IW;

    const int il = t >> 5;             // this thread's i-row (0..7)
    const int e4 = (t & 31) * 4;       // this thread's e-offset

    __shared__ float sA[IW][Nc];       // adj[b, i0:i0+8, :]  (8 KB)
    __shared__ float sT[IW][Dc];       // finished T tile     (4 KB)

    // stage adj rows: contiguous 8 KB copy
    {
        const float* ap = adj + ((size_t)b * Nc + i0) * Nc;
        #pragma unroll
        for (int k = 0; k < 8; ++k)
            ((float*)sA)[t + k * 256] = ap[t + k * 256];
    }
    __syncthreads();

    // main j-loop: per j read the 4 KB chunk dep[b,j,i0:i0+8,:]
    const float* depP = dep + (((size_t)b * Nc) * Nc + i0) * Dc + t * 4;
    const float* hidP = hidden + (size_t)b * Nc * Dc + e4;

    floatx4 acc = {0.f, 0.f, 0.f, 0.f};

    for (int j0 = 0; j0 < Nc; j0 += 8) {
        floatx4 d[8];
        #pragma unroll
        for (int k = 0; k < 8; ++k)
            d[k] = __builtin_nontemporal_load(
                (const floatx4*)(depP + (size_t)(j0 + k) * Nc * Dc));
        #pragma unroll
        for (int k = 0; k < 8; ++k) {
            const floatx4 h = *(const floatx4*)(hidP + (size_t)(j0 + k) * Dc);
            const float   a = sA[il][j0 + k];   // uniform per 32-lane group: broadcast
            acc += a * (d[k] + h);
        }
    }

    *(floatx4*)&sT[il][e4] = acc;
    __syncthreads();

    // out[b,i0+r,d] = sum_e sT[r][e]*W[e,d] + bias[d]
    // thread (h = e-half, d): partial over 64 e for all 8 rows, combine via sO
    __shared__ float sO[2][IW][Dc];
    {
        const int d = t & (Dc - 1);
        const int h = t >> 7;
        const float* wp = W + (size_t)(h * 64) * Dc + d;
        float o[IW];
        #pragma unroll
        for (int r = 0; r < IW; ++r) o[r] = 0.f;
        for (int e = 0; e < 64; ++e) {
            const float w = wp[(size_t)e * Dc];
            #pragma unroll
            for (int r = 0; r < IW; ++r)
                o[r] = fmaf(sT[r][h * 64 + e], w, o[r]);
        }
        #pragma unroll
        for (int r = 0; r < IW; ++r) sO[h][r][d] = o[r];
    }
    __syncthreads();

    // write: 1024 outputs, 4 per thread, coalesced
    {
        float* op = out + ((size_t)b * Nc + i0) * Dc;
        #pragma unroll
        for (int k = 0; k < 4; ++k) {
            const int idx = t + k * 256;         // r*128 + d
            const int r   = idx >> 7;
            const int d   = idx & (Dc - 1);
            op[idx] = sO[0][r][d] + sO[1][r][d] + bias[d];
        }
    }
}

extern "C" void kernel_launch(void* const* d_in, const int* in_sizes, int n_in,
                              void* d_out, int out_size, void* d_ws, size_t ws_size,
                              hipStream_t stream) {
    const float* hidden = (const float*)d_in[0];
    const float* adj    = (const float*)d_in[1];
    const float* dep    = (const float*)d_in[2];
    const float* W      = (const float*)d_in[3];
    const float* bias   = (const float*)d_in[4];
    float* out          = (float*)d_out;

    depgcn_fused<<<dim3(Bc * NB), dim3(256), 0, stream>>>(hidden, adj, dep, W, bias, out);
}